// Round 7
// baseline (2782.625 us; speedup 1.0000x reference)
//
#include <hip/hip_runtime.h>
#include <hip/hip_bf16.h>
#include <stdint.h>

#define NTOK 49

typedef __bf16 bf16x8 __attribute__((ext_vector_type(8)));
typedef float f32x4 __attribute__((ext_vector_type(4)));

__device__ __forceinline__ uint16_t f2bf(float f){
  uint32_t x = __float_as_uint(f);
  uint32_t r = (x + 0x7fffu + ((x >> 16) & 1u)) >> 16;
  return (uint16_t)r;
}

// swizzled 16B read from a 64-wide (128B-stride) LDS tile
#define LDS_LD8(buf, row, kelem) \
  __builtin_bit_cast(bf16x8, *(const uint4*)((const char*)(buf) + (row)*128 + ((((kelem)*2)) ^ ((((row))&7)<<4))))

__global__ void prep_kernel(const float* __restrict__ Wqkv,
                            const float* __restrict__ Wout,
                            const float* __restrict__ btab,
                            const int* __restrict__ ridx,
                            uint16_t* __restrict__ WqkvT,
                            uint16_t* __restrict__ WoutT,
                            float* __restrict__ biasPre){
  const int T1 = 1536*256, T2 = 256*512, T3 = 8*2401;
  for (int i = blockIdx.x*blockDim.x + threadIdx.x; i < T1+T2+T3; i += gridDim.x*blockDim.x){
    if (i < T1){ int n = i/256, k = i%256; WqkvT[i] = f2bf(Wqkv[k*1536 + n]); }
    else if (i < T1+T2){ int j = i - T1; int n = j/512, k = j%512; WoutT[j] = f2bf(Wout[k*256 + n]); }
    else { int j = i - T1 - T2; int h = j/2401, ij = j%2401; biasPre[j] = btab[ridx[ij]*8 + h]; }
  }
}

// 512 threads / 8 waves, one window per block.
// LDS: xn 25600 + qs 6400 + ks 6400 + vt 8192 + ps 6400 + os 6400 = 59392 B -> 2 blocks/CU.
// Regs capped at 128 total (VGPR+AGPR unified) -> 4 waves/SIMD: 2x the R2..R6 occupancy.
__global__ __launch_bounds__(512, 4)
void maxvit_fused(const float* __restrict__ x,
                  const float* __restrict__ gamma,
                  const float* __restrict__ beta,
                  const uint16_t* __restrict__ WqkvT,   // bf16 [1536][256]
                  const uint16_t* __restrict__ WoutT,   // bf16 [256][512]
                  const float*    __restrict__ bout,    // [256]
                  const float*    __restrict__ biasPre, // [8][49][49]
                  float* __restrict__ out)              // [B][49][256] fp32
{
  __shared__ uint16_t xn[50*256];  // row 49 = zeros; reads of rows>49 clamp to 49
  __shared__ uint16_t qs[50*64];
  __shared__ uint16_t ks[50*64];
  __shared__ uint16_t vt[64*64];   // V transposed: [d][token]
  __shared__ uint16_t ps[50*64];   // P (strips written by waves 0-3)
  __shared__ uint16_t os[50*64];   // O_h

  const int b    = blockIdx.x;
  const int tid  = threadIdx.x;
  const int wave = tid >> 6;
  const int lane = tid & 63;
  const int lo   = lane & 15;
  const int g    = lane >> 4;
  const int wm   = wave & 3;       // token-strip owner for attention phases
  const int wn   = wave >> 2;      // col-half owner for PV
  const f32x4 fzero = {0.f, 0.f, 0.f, 0.f};

  // ---------------- LayerNorm (R2-identical row math, 8-wave distribution) ----------------
  {
    const int c0 = lane * 4;
    float4 gm = *(const float4*)(gamma + c0);
    float4 bt = *(const float4*)(beta  + c0);
    for (int r = wave; r < 50; r += 8){
      char* dst = (char*)xn + r*512 + ((c0*2) ^ ((r&7)<<4));
      if (r < NTOK){
        float4 u = *(const float4*)(x + ((size_t)(b*NTOK + r))*256 + c0);
        float s  = u.x+u.y+u.z+u.w;
        float ss = u.x*u.x+u.y*u.y+u.z*u.z+u.w*u.w;
        #pragma unroll
        for (int d = 1; d < 64; d <<= 1){ s += __shfl_xor(s, d); ss += __shfl_xor(ss, d); }
        float mu  = s  * (1.0f/256.0f);
        float var = ss * (1.0f/256.0f) - mu*mu;
        float rs  = rsqrtf(var + 1e-5f);
        ushort4 o;
        o.x = f2bf((u.x-mu)*rs*gm.x+bt.x);
        o.y = f2bf((u.y-mu)*rs*gm.y+bt.y);
        o.z = f2bf((u.z-mu)*rs*gm.z+bt.z);
        o.w = f2bf((u.w-mu)*rs*gm.w+bt.w);
        *(ushort4*)dst = o;
      } else {
        ushort4 z; z.x = z.y = z.z = z.w = 0;
        *(ushort4*)dst = z;
      }
    }
  }
  __syncthreads();

  f32x4 outacc[4][2];
  #pragma unroll
  for (int m = 0; m < 4; m++){ outacc[m][0] = fzero; outacc[m][1] = fzero; }

  // proj tile map: wave covers m-tile (wave>>1) and 6 of 12 unit-tiles.
  // unit-tile nt: 0-3 = Q d-tiles, 4-7 = K d-tiles, 8-11 = V d-tiles.
  const int mt     = wave >> 1;
  const int ntbase = (wave & 1) * 6;

  for (int h = 0; h < 8; ++h){
    // ===== Phase 1: QKV projection, 6 tiles per wave =====
    {
      f32x4 acc[6];
      #pragma unroll
      for (int t = 0; t < 6; t++) acc[t] = fzero;
      const uint16_t* wp[6];
      #pragma unroll
      for (int t = 0; t < 6; t++){
        const int nt  = ntbase + t;
        const int sel = nt >> 2;        // 0=Q 1=K 2=V (wave-uniform)
        const int dt  = nt & 3;
        wp[t] = WqkvT + (size_t)(sel*512 + h*64 + dt*16 + lo)*256;
      }
      int xrow = mt*16 + lo;
      if (mt == 3) xrow = (xrow < 49) ? xrow : 49;   // xn row 49 = zeros
      #pragma unroll
      for (int k0 = 0; k0 < 256; k0 += 32){
        const int kb = k0 + g*8;
        bf16x8 afr = __builtin_bit_cast(bf16x8,
          *(const uint4*)((const char*)xn + xrow*512 + ((kb*2) ^ ((xrow&7)<<4))));
        #pragma unroll
        for (int t = 0; t < 6; t++){
          bf16x8 bb = __builtin_bit_cast(bf16x8, *(const uint4*)(wp[t] + kb));
          acc[t] = __builtin_amdgcn_mfma_f32_16x16x32_bf16(afr, bb, acc[t], 0, 0, 0);
        }
      }
      // stores (R2 per-element pattern; C: col=unit(lo), row=token(g*4+r))
      #pragma unroll
      for (int t = 0; t < 6; t++){
        const int nt  = ntbase + t;
        const int sel = nt >> 2;
        const int d   = (nt & 3)*16 + lo;
        #pragma unroll
        for (int r = 0; r < 4; r++){
          const int token = mt*16 + g*4 + r;
          if (sel == 2){
            *(uint16_t*)((char*)vt + d*128 + ((token*2) ^ ((d&7)<<4))) = f2bf(acc[t][r]);
          } else {
            const int tok = (token < 49) ? token : 49;   // racers write identical values
            uint16_t* buf = (sel == 0) ? qs : ks;
            const float v = (sel == 0) ? acc[t][r]*0.125f : acc[t][r];
            *(uint16_t*)((char*)buf + tok*128 + ((d*2) ^ ((tok&7)<<4))) = f2bf(v);
          }
        }
      }
    }
    __syncthreads();   // B1: qs/ks/vt complete

    // ===== Phase 2: S = q k^T (+bias, mask) + softmax for strip wm (dup by wn) =====
    {
      f32x4 s[4];
      #pragma unroll
      for (int n = 0; n < 4; n++) s[n] = fzero;
      int qrow = wm*16 + lo; qrow = (qrow < 49) ? qrow : 49;
      bf16x8 a0 = LDS_LD8(qs, qrow, g*8);
      bf16x8 a1 = LDS_LD8(qs, qrow, 32 + g*8);
      #pragma unroll
      for (int n = 0; n < 4; n++){
        int krow = n*16 + lo;
        if (n == 3) krow = (krow < 49) ? krow : 49;
        bf16x8 b0 = LDS_LD8(ks, krow, g*8);
        bf16x8 b1 = LDS_LD8(ks, krow, 32 + g*8);
        s[n] = __builtin_amdgcn_mfma_f32_16x16x32_bf16(a0, b0, s[n], 0, 0, 0);
        s[n] = __builtin_amdgcn_mfma_f32_16x16x32_bf16(a1, b1, s[n], 0, 0, 0);
      }
      const float* bp = biasPre + h*2401;
      #pragma unroll
      for (int n = 0; n < 4; n++){
        const int j = n*16 + lo;
        #pragma unroll
        for (int r = 0; r < 4; r++){
          const int i = wm*16 + g*4 + r;
          float v = s[n][r];
          if (j < NTOK){ if (i < NTOK) v += bp[i*49 + j]; }
          else v = -1e30f;
          s[n][r] = v;
        }
      }
      float mx[4], sm[4];
      #pragma unroll
      for (int r = 0; r < 4; r++){
        float m0 = fmaxf(fmaxf(s[0][r], s[1][r]), fmaxf(s[2][r], s[3][r]));
        #pragma unroll
        for (int d = 1; d < 16; d <<= 1) m0 = fmaxf(m0, __shfl_xor(m0, d));
        mx[r] = m0;
        sm[r] = 0.f;
      }
      #pragma unroll
      for (int n = 0; n < 4; n++)
        #pragma unroll
        for (int r = 0; r < 4; r++){ float p = __expf(s[n][r] - mx[r]); s[n][r] = p; sm[r] += p; }
      #pragma unroll
      for (int r = 0; r < 4; r++){
        float t = sm[r];
        #pragma unroll
        for (int d = 1; d < 16; d <<= 1) t += __shfl_xor(t, d);
        sm[r] = 1.0f / t;
      }
      if (wn == 0){
        #pragma unroll
        for (int n = 0; n < 4; n++){
          const int j = n*16 + lo;
          #pragma unroll
          for (int r = 0; r < 4; r++){
            int i = wm*16 + g*4 + r; i = (i < 49) ? i : 49;  // racers identical
            *(uint16_t*)((char*)ps + i*128 + ((j*2) ^ ((i&7)<<4))) = f2bf(s[n][r]*sm[r]);
          }
        }
      }
    }
    __syncthreads();   // B2: ps complete

    // ===== Phase 3: O = P V (strip wm, col-half wn) =====
    {
      f32x4 o[2];
      o[0] = fzero; o[1] = fzero;
      int prow = wm*16 + lo; prow = (prow < 49) ? prow : 49;
      bf16x8 a0 = LDS_LD8(ps, prow, g*8);
      bf16x8 a1 = LDS_LD8(ps, prow, 32 + g*8);
      #pragma unroll
      for (int n2 = 0; n2 < 2; n2++){
        const int vrow = wn*32 + n2*16 + lo;
        bf16x8 b0 = LDS_LD8(vt, vrow, g*8);
        bf16x8 b1 = LDS_LD8(vt, vrow, 32 + g*8);
        o[n2] = __builtin_amdgcn_mfma_f32_16x16x32_bf16(a0, b0, o[n2], 0, 0, 0);
        o[n2] = __builtin_amdgcn_mfma_f32_16x16x32_bf16(a1, b1, o[n2], 0, 0, 0);
      }
      #pragma unroll
      for (int n2 = 0; n2 < 2; n2++){
        const int d = wn*32 + n2*16 + lo;
        #pragma unroll
        for (int r = 0; r < 4; r++){
          int token = wm*16 + g*4 + r; token = (token < 49) ? token : 49;  // racers identical
          *(uint16_t*)((char*)os + token*128 + ((d*2) ^ ((token&7)<<4))) = f2bf(o[n2][r]);
        }
      }
    }
    __syncthreads();   // B3: os complete

    // ===== Phase 4: out-projection accumulate (2 col-tiles per wave) =====
    #pragma unroll
    for (int kk = 0; kk < 2; ++kk){
      const int kb = kk*32 + g*8;
      bf16x8 afr[4];
      #pragma unroll
      for (int m = 0; m < 4; m++){
        int row = m*16 + lo;
        if (m == 3) row = (row < 49) ? row : 49;
        afr[m] = LDS_LD8(os, row, kb);
      }
      #pragma unroll
      for (int n2 = 0; n2 < 2; n2++){
        const int ncol = wave*32 + n2*16 + lo;
        bf16x8 bb = __builtin_bit_cast(bf16x8,
          *(const uint4*)(WoutT + (size_t)ncol*512 + h*64 + kb));
        #pragma unroll
        for (int m = 0; m < 4; m++)
          outacc[m][n2] = __builtin_amdgcn_mfma_f32_16x16x32_bf16(afr[m], bb, outacc[m][n2], 0, 0, 0);
      }
    }
    // no barrier: next phase-1 writes qs/ks/vt (disjoint from os); B2(h+1) precedes next os write
  }

  // ---------------- epilogue: +b_out, store fp32 ----------------
  {
    float bo0 = bout[wave*32 + lo];
    float bo1 = bout[wave*32 + 16 + lo];
    #pragma unroll
    for (int m = 0; m < 4; m++){
      #pragma unroll
      for (int r = 0; r < 4; r++){
        const int token = m*16 + g*4 + r;
        if (token < NTOK){
          float* po = out + ((size_t)(b*NTOK + token))*256 + wave*32 + lo;
          po[0]  = outacc[m][0][r] + bo0;
          po[16] = outacc[m][1][r] + bo1;
        }
      }
    }
  }
}

extern "C" void kernel_launch(void* const* d_in, const int* in_sizes, int n_in,
                              void* d_out, int out_size, void* d_ws, size_t ws_size,
                              hipStream_t stream){
  const float* x     = (const float*)d_in[0];
  const float* gamma = (const float*)d_in[1];
  const float* beta  = (const float*)d_in[2];
  const float* Wqkv  = (const float*)d_in[3];
  const float* Wout  = (const float*)d_in[4];
  const float* bout  = (const float*)d_in[5];
  const float* btab  = (const float*)d_in[6];
  const int*   ridx  = (const int*)d_in[7];

  uint16_t* WqkvT   = (uint16_t*)d_ws;                          // 786432 B
  uint16_t* WoutT   = (uint16_t*)((char*)d_ws + 786432);        // 262144 B
  float*    biasPre = (float*)((char*)d_ws + 786432 + 262144);  // 76832 B

  prep_kernel<<<512, 256, 0, stream>>>(Wqkv, Wout, btab, ridx, WqkvT, WoutT, biasPre);
  maxvit_fused<<<4096, 512, 0, stream>>>(x, gamma, beta, WqkvT, WoutT, bout, biasPre,
                                         (float*)d_out);
}

// Round 10
// 1592.389 us; speedup vs baseline: 1.7475x; 1.7475x over previous
//
#include <hip/hip_runtime.h>
#include <hip/hip_bf16.h>
#include <stdint.h>

#define NTOK 49

typedef __bf16 bf16x8 __attribute__((ext_vector_type(8)));
typedef float f32x4 __attribute__((ext_vector_type(4)));

__device__ __forceinline__ uint16_t f2bf(float f){
  uint32_t x = __float_as_uint(f);
  uint32_t r = (x + 0x7fffu + ((x >> 16) & 1u)) >> 16;
  return (uint16_t)r;
}

// swizzled 16B read from a 64-wide (128B-stride) LDS tile
#define LDS_LD8(buf, row, kelem) \
  __builtin_bit_cast(bf16x8, *(const uint4*)((const char*)(buf) + (row)*128 + ((((kelem)*2)) ^ ((((row))&7)<<4))))
// swizzled 16B read from a 256-wide (512B-stride) LDS tile (xn!)
#define LDS_LD8X(buf, row, kelem) \
  __builtin_bit_cast(bf16x8, *(const uint4*)((const char*)(buf) + (row)*512 + ((((kelem)*2)) ^ ((((row))&7)<<4))))

__global__ void prep_kernel(const float* __restrict__ Wqkv,
                            const float* __restrict__ Wout,
                            const float* __restrict__ btab,
                            const int* __restrict__ ridx,
                            uint16_t* __restrict__ WqkvT,
                            uint16_t* __restrict__ WoutT,
                            float* __restrict__ biasPre){
  const int T1 = 1536*256, T2 = 256*512, T3 = 8*2401;
  for (int i = blockIdx.x*blockDim.x + threadIdx.x; i < T1+T2+T3; i += gridDim.x*blockDim.x){
    if (i < T1){ int n = i/256, k = i%256; WqkvT[i] = f2bf(Wqkv[k*1536 + n]); }
    else if (i < T1+T2){ int j = i - T1; int n = j/512, k = j%512; WoutT[j] = f2bf(Wout[k*256 + n]); }
    else { int j = i - T1 - T2; int h = j/2401, ij = j%2401; biasPre[j] = btab[ridx[ij]*8 + h]; }
  }
}

// LDS: xn 50*256*2=25600, qs/ks/ps 50*64*2=6400 each, vt 64*64*2=8192 -> 52992 B
// 3 blocks/CU by LDS (3*53248=159744 <= 163840).
// QKV projection split into QK-pass (32 acc) + V-pass (16 acc) so peak live regs
// fit the (256,3) budget (512/3 = 170 unified VGPR+AGPR) WITHOUT spilling.
__global__ __launch_bounds__(256, 3)
void maxvit_fused(const float* __restrict__ x,
                  const float* __restrict__ gamma,
                  const float* __restrict__ beta,
                  const uint16_t* __restrict__ WqkvT,   // bf16 [1536][256]
                  const uint16_t* __restrict__ WoutT,   // bf16 [256][512]
                  const float*    __restrict__ bout,    // [256]
                  const float*    __restrict__ biasPre, // [8][49][49]
                  float* __restrict__ out)              // [B][49][256] fp32
{
  __shared__ uint16_t xn[50*256];  // row 49 = zeros; reads of rows>49 clamp to 49
  __shared__ uint16_t qs[50*64];
  __shared__ uint16_t ks[50*64];
  __shared__ uint16_t ps[50*64];   // P, then reused for O_h
  __shared__ uint16_t vt[64*64];   // V transposed: [d][token]

  const int b    = blockIdx.x;
  const int tid  = threadIdx.x;
  const int wave = tid >> 6;
  const int lane = tid & 63;
  const int lo   = lane & 15;
  const int g    = lane >> 4;
  const f32x4 fzero = {0.f, 0.f, 0.f, 0.f};

  // ---------------- LayerNorm (R2/R5-identical math) ----------------
  {
    const int c0 = lane * 4;
    float4 gm = *(const float4*)(gamma + c0);
    float4 bt = *(const float4*)(beta  + c0);
    for (int r = wave; r < 50; r += 4){
      char* dst = (char*)xn + r*512 + ((c0*2) ^ ((r&7)<<4));
      if (r < NTOK){
        float4 u = *(const float4*)(x + ((size_t)(b*NTOK + r))*256 + c0);
        float s  = u.x+u.y+u.z+u.w;
        float ss = u.x*u.x+u.y*u.y+u.z*u.z+u.w*u.w;
        #pragma unroll
        for (int d = 1; d < 64; d <<= 1){ s += __shfl_xor(s, d); ss += __shfl_xor(ss, d); }
        float mu  = s  * (1.0f/256.0f);
        float var = ss * (1.0f/256.0f) - mu*mu;
        float rs  = rsqrtf(var + 1e-5f);
        ushort4 o;
        o.x = f2bf((u.x-mu)*rs*gm.x+bt.x);
        o.y = f2bf((u.y-mu)*rs*gm.y+bt.y);
        o.z = f2bf((u.z-mu)*rs*gm.z+bt.z);
        o.w = f2bf((u.w-mu)*rs*gm.w+bt.w);
        *(ushort4*)dst = o;
      } else {
        ushort4 z; z.x = z.y = z.z = z.w = 0;
        *(ushort4*)dst = z;
      }
    }
  }
  __syncthreads();

  f32x4 outacc[4][4];
  #pragma unroll
  for (int m = 0; m < 4; m++)
    #pragma unroll
    for (int n = 0; n < 4; n++) outacc[m][n] = fzero;

  for (int h = 0; h < 8; ++h){
    // ---------------- QK projection pass (32 acc regs) ----------------
    {
      f32x4 aq[4], ak[4];
      #pragma unroll
      for (int m = 0; m < 4; m++){ aq[m] = fzero; ak[m] = fzero; }
      const uint16_t* pq = WqkvT + (size_t)(       h*64 + wave*16 + lo)*256;
      const uint16_t* pk = WqkvT + (size_t)( 512 + h*64 + wave*16 + lo)*256;
      #pragma unroll
      for (int k0 = 0; k0 < 256; k0 += 32){
        const int kb = k0 + g*8;
        bf16x8 afr[4];
        #pragma unroll
        for (int m = 0; m < 4; m++){
          int row = m*16 + lo;
          if (m == 3) row = (row < 49) ? row : 49;   // xn row 49 = zeros
          afr[m] = LDS_LD8X(xn, row, kb);            // 512B-stride read (R9 bug: was 128B)
        }
        bf16x8 fq = __builtin_bit_cast(bf16x8, *(const uint4*)(pq + kb));
        bf16x8 fk = __builtin_bit_cast(bf16x8, *(const uint4*)(pk + kb));
        #pragma unroll
        for (int m = 0; m < 4; m++){
          aq[m] = __builtin_amdgcn_mfma_f32_16x16x32_bf16(afr[m], fq, aq[m], 0, 0, 0);
          ak[m] = __builtin_amdgcn_mfma_f32_16x16x32_bf16(afr[m], fk, ak[m], 0, 0, 0);
        }
      }
      const int d = wave*16 + lo;
      #pragma unroll
      for (int m = 0; m < 4; m++){
        #pragma unroll
        for (int r = 0; r < 4; r++){
          const int token = m*16 + g*4 + r;
          const int tok   = (token < 49) ? token : 49;   // racers write identical values
          *(uint16_t*)((char*)qs + tok*128 + ((d*2) ^ ((tok&7)<<4))) = f2bf(aq[m][r]*0.125f);
          *(uint16_t*)((char*)ks + tok*128 + ((d*2) ^ ((tok&7)<<4))) = f2bf(ak[m][r]);
        }
      }
    }
    // ---------------- V projection pass (16 acc regs) ----------------
    {
      f32x4 av[4];
      #pragma unroll
      for (int m = 0; m < 4; m++) av[m] = fzero;
      const uint16_t* pv = WqkvT + (size_t)(1024 + h*64 + wave*16 + lo)*256;
      #pragma unroll
      for (int k0 = 0; k0 < 256; k0 += 32){
        const int kb = k0 + g*8;
        bf16x8 afr[4];
        #pragma unroll
        for (int m = 0; m < 4; m++){
          int row = m*16 + lo;
          if (m == 3) row = (row < 49) ? row : 49;
          afr[m] = LDS_LD8X(xn, row, kb);
        }
        bf16x8 fv = __builtin_bit_cast(bf16x8, *(const uint4*)(pv + kb));
        #pragma unroll
        for (int m = 0; m < 4; m++)
          av[m] = __builtin_amdgcn_mfma_f32_16x16x32_bf16(afr[m], fv, av[m], 0, 0, 0);
      }
      const int d = wave*16 + lo;
      #pragma unroll
      for (int m = 0; m < 4; m++){
        #pragma unroll
        for (int r = 0; r < 4; r++){
          const int token = m*16 + g*4 + r;
          *(uint16_t*)((char*)vt + d*128 + ((token*2) ^ ((d&7)<<4))) = f2bf(av[m][r]);
        }
      }
    }
    __syncthreads();   // (i) qs/ks/vt complete

    // ---------------- S = q k^T (+bias, mask) ----------------
    f32x4 s[4];
    #pragma unroll
    for (int n = 0; n < 4; n++) s[n] = fzero;
    {
      int qrow = wave*16 + lo; qrow = (qrow < 49) ? qrow : 49;
      bf16x8 a0 = LDS_LD8(qs, qrow, g*8);
      bf16x8 a1 = LDS_LD8(qs, qrow, 32 + g*8);
      #pragma unroll
      for (int n = 0; n < 4; n++){
        int krow = n*16 + lo;
        if (n == 3) krow = (krow < 49) ? krow : 49;
        bf16x8 b0 = LDS_LD8(ks, krow, g*8);
        bf16x8 b1 = LDS_LD8(ks, krow, 32 + g*8);
        s[n] = __builtin_amdgcn_mfma_f32_16x16x32_bf16(a0, b0, s[n], 0, 0, 0);
        s[n] = __builtin_amdgcn_mfma_f32_16x16x32_bf16(a1, b1, s[n], 0, 0, 0);
      }
    }
    {
      const float* bp = biasPre + h*2401;
      #pragma unroll
      for (int n = 0; n < 4; n++){
        const int j = n*16 + lo;
        #pragma unroll
        for (int r = 0; r < 4; r++){
          const int i = wave*16 + g*4 + r;
          float v = s[n][r];
          if (j < NTOK){ if (i < NTOK) v += bp[i*49 + j]; }
          else v = -1e30f;
          s[n][r] = v;
        }
      }
      // softmax over j: each score row lives in one 16-lane group
      float mx[4], sm[4];
      #pragma unroll
      for (int r = 0; r < 4; r++){
        float m0 = fmaxf(fmaxf(s[0][r], s[1][r]), fmaxf(s[2][r], s[3][r]));
        #pragma unroll
        for (int d = 1; d < 16; d <<= 1) m0 = fmaxf(m0, __shfl_xor(m0, d));
        mx[r] = m0;
        sm[r] = 0.f;
      }
      #pragma unroll
      for (int n = 0; n < 4; n++)
        #pragma unroll
        for (int r = 0; r < 4; r++){ float p = __expf(s[n][r] - mx[r]); s[n][r] = p; sm[r] += p; }
      #pragma unroll
      for (int r = 0; r < 4; r++){
        float t = sm[r];
        #pragma unroll
        for (int d = 1; d < 16; d <<= 1) t += __shfl_xor(t, d);
        sm[r] = 1.0f / t;
      }
      // write P (wave-private strip -> no barrier before PV)
      #pragma unroll
      for (int n = 0; n < 4; n++){
        const int j = n*16 + lo;
        #pragma unroll
        for (int r = 0; r < 4; r++){
          int i = wave*16 + g*4 + r; i = (i < 49) ? i : 49;  // racers identical
          *(uint16_t*)((char*)ps + i*128 + ((j*2) ^ ((i&7)<<4))) = f2bf(s[n][r]*sm[r]);
        }
      }
    }

    // ---------------- O = P V ----------------
    f32x4 o[4];
    #pragma unroll
    for (int n = 0; n < 4; n++) o[n] = fzero;
    {
      int prow = wave*16 + lo; prow = (prow < 49) ? prow : 49;
      bf16x8 a0 = LDS_LD8(ps, prow, g*8);
      bf16x8 a1 = LDS_LD8(ps, prow, 32 + g*8);
      #pragma unroll
      for (int n = 0; n < 4; n++){
        const int vrow = n*16 + lo;
        bf16x8 b0 = LDS_LD8(vt, vrow, g*8);
        bf16x8 b1 = LDS_LD8(vt, vrow, 32 + g*8);
        o[n] = __builtin_amdgcn_mfma_f32_16x16x32_bf16(a0, b0, o[n], 0, 0, 0);
        o[n] = __builtin_amdgcn_mfma_f32_16x16x32_bf16(a1, b1, o[n], 0, 0, 0);
      }
    }
    // write O_h into ps (own strip; own wave already consumed its P rows)
    #pragma unroll
    for (int n = 0; n < 4; n++){
      const int d = n*16 + lo;
      #pragma unroll
      for (int r = 0; r < 4; r++){
        int token = wave*16 + g*4 + r; token = (token < 49) ? token : 49;  // racers identical
        *(uint16_t*)((char*)ps + token*128 + ((d*2) ^ ((token&7)<<4))) = f2bf(o[n][r]);
      }
    }
    __syncthreads();   // (ii) O_h complete (read cross-wave next)

    // ---------------- out-projection accumulate ----------------
    #pragma unroll
    for (int kk = 0; kk < 2; ++kk){
      const int kb = kk*32 + g*8;
      bf16x8 afr[4];
      #pragma unroll
      for (int m = 0; m < 4; m++){
        int row = m*16 + lo;
        if (m == 3) row = (row < 49) ? row : 49;
        afr[m] = LDS_LD8(ps, row, kb);
      }
      #pragma unroll
      for (int n = 0; n < 4; n++){
        const int ncol = wave*64 + n*16 + lo;
        bf16x8 bb = __builtin_bit_cast(bf16x8,
          *(const uint4*)(WoutT + (size_t)ncol*512 + h*64 + kb));
        #pragma unroll
        for (int m = 0; m < 4; m++)
          outacc[m][n] = __builtin_amdgcn_mfma_f32_16x16x32_bf16(afr[m], bb, outacc[m][n], 0, 0, 0);
      }
    }
  }

  // ---------------- epilogue: +b_out, store fp32 ----------------
  #pragma unroll
  for (int n = 0; n < 4; n++){
    const int col = wave*64 + n*16 + lo;
    const float bo = bout[col];
    #pragma unroll
    for (int m = 0; m < 4; m++){
      #pragma unroll
      for (int r = 0; r < 4; r++){
        const int token = m*16 + g*4 + r;
        if (token < NTOK)
          out[((size_t)(b*NTOK + token))*256 + col] = outacc[m][n][r] + bo;
      }
    }
  }
}

extern "C" void kernel_launch(void* const* d_in, const int* in_sizes, int n_in,
                              void* d_out, int out_size, void* d_ws, size_t ws_size,
                              hipStream_t stream){
  const float* x     = (const float*)d_in[0];
  const float* gamma = (const float*)d_in[1];
  const float* beta  = (const float*)d_in[2];
  const float* Wqkv  = (const float*)d_in[3];
  const float* Wout  = (const float*)d_in[4];
  const float* bout  = (const float*)d_in[5];
  const float* btab  = (const float*)d_in[6];
  const int*   ridx  = (const int*)d_in[7];

  uint16_t* WqkvT   = (uint16_t*)d_ws;                          // 786432 B
  uint16_t* WoutT   = (uint16_t*)((char*)d_ws + 786432);        // 262144 B
  float*    biasPre = (float*)((char*)d_ws + 786432 + 262144);  // 76832 B

  prep_kernel<<<512, 256, 0, stream>>>(Wqkv, Wout, btab, ridx, WqkvT, WoutT, biasPre);
  maxvit_fused<<<4096, 256, 0, stream>>>(x, gamma, beta, WqkvT, WoutT, bout, biasPre,
                                         (float*)d_out);
}

// Round 11
// 1565.919 us; speedup vs baseline: 1.7770x; 1.0169x over previous
//
#include <hip/hip_runtime.h>
#include <hip/hip_bf16.h>
#include <stdint.h>

#define NTOK 49

typedef __bf16 bf16x8 __attribute__((ext_vector_type(8)));
typedef float f32x4 __attribute__((ext_vector_type(4)));

__device__ __forceinline__ uint16_t f2bf(float f){
  uint32_t x = __float_as_uint(f);
  uint32_t r = (x + 0x7fffu + ((x >> 16) & 1u)) >> 16;
  return (uint16_t)r;
}

// swizzled 16B read from a 64-wide (128B-stride) LDS tile
#define LDS_LD8(buf, row, kelem) \
  __builtin_bit_cast(bf16x8, *(const uint4*)((const char*)(buf) + (row)*128 + ((((kelem)*2)) ^ ((((row))&7)<<4))))
// swizzled 16B read from a 256-wide (512B-stride) LDS tile (xn!)
#define LDS_LD8X(buf, row, kelem) \
  __builtin_bit_cast(bf16x8, *(const uint4*)((const char*)(buf) + (row)*512 + ((((kelem)*2)) ^ ((((row))&7)<<4))))

__global__ void prep_kernel(const float* __restrict__ Wqkv,
                            const float* __restrict__ Wout,
                            const float* __restrict__ btab,
                            const int* __restrict__ ridx,
                            uint16_t* __restrict__ WqkvT,
                            uint16_t* __restrict__ WoutT,
                            float* __restrict__ biasPre){
  const int T1 = 1536*256, T2 = 256*512, T3 = 8*2401;
  for (int i = blockIdx.x*blockDim.x + threadIdx.x; i < T1+T2+T3; i += gridDim.x*blockDim.x){
    if (i < T1){ int n = i/256, k = i%256; WqkvT[i] = f2bf(Wqkv[k*1536 + n]); }
    else if (i < T1+T2){ int j = i - T1; int n = j/512, k = j%512; WoutT[j] = f2bf(Wout[k*256 + n]); }
    else { int j = i - T1 - T2; int h = j/2401, ij = j%2401; biasPre[j] = btab[ridx[ij]*8 + h]; }
  }
}

// LDS: xn 50*256*2=25600, qs/ks/ps 50*64*2=6400 each, vt 64*64*2=8192 -> 52992 B
// 3 blocks/CU by LDS (3*53248=159744 <= 163840).
// QKV projection split into THREE passes (Q, K, V), each only 16 acc regs, so peak
// AGPR = outacc(64)+16 = 80 fits the (256,3) split (R10: QK-pass needed 96 acc -> acc spill, 1.9GB).
__global__ __launch_bounds__(256, 3)
void maxvit_fused(const float* __restrict__ x,
                  const float* __restrict__ gamma,
                  const float* __restrict__ beta,
                  const uint16_t* __restrict__ WqkvT,   // bf16 [1536][256]
                  const uint16_t* __restrict__ WoutT,   // bf16 [256][512]
                  const float*    __restrict__ bout,    // [256]
                  const float*    __restrict__ biasPre, // [8][49][49]
                  float* __restrict__ out)              // [B][49][256] fp32
{
  __shared__ uint16_t xn[50*256];  // row 49 = zeros; reads of rows>49 clamp to 49
  __shared__ uint16_t qs[50*64];
  __shared__ uint16_t ks[50*64];
  __shared__ uint16_t ps[50*64];   // P, then reused for O_h
  __shared__ uint16_t vt[64*64];   // V transposed: [d][token]

  const int b    = blockIdx.x;
  const int tid  = threadIdx.x;
  const int wave = tid >> 6;
  const int lane = tid & 63;
  const int lo   = lane & 15;
  const int g    = lane >> 4;
  const f32x4 fzero = {0.f, 0.f, 0.f, 0.f};

  // ---------------- LayerNorm (R2/R5-identical math) ----------------
  {
    const int c0 = lane * 4;
    float4 gm = *(const float4*)(gamma + c0);
    float4 bt = *(const float4*)(beta  + c0);
    for (int r = wave; r < 50; r += 4){
      char* dst = (char*)xn + r*512 + ((c0*2) ^ ((r&7)<<4));
      if (r < NTOK){
        float4 u = *(const float4*)(x + ((size_t)(b*NTOK + r))*256 + c0);
        float s  = u.x+u.y+u.z+u.w;
        float ss = u.x*u.x+u.y*u.y+u.z*u.z+u.w*u.w;
        #pragma unroll
        for (int d = 1; d < 64; d <<= 1){ s += __shfl_xor(s, d); ss += __shfl_xor(ss, d); }
        float mu  = s  * (1.0f/256.0f);
        float var = ss * (1.0f/256.0f) - mu*mu;
        float rs  = rsqrtf(var + 1e-5f);
        ushort4 o;
        o.x = f2bf((u.x-mu)*rs*gm.x+bt.x);
        o.y = f2bf((u.y-mu)*rs*gm.y+bt.y);
        o.z = f2bf((u.z-mu)*rs*gm.z+bt.z);
        o.w = f2bf((u.w-mu)*rs*gm.w+bt.w);
        *(ushort4*)dst = o;
      } else {
        ushort4 z; z.x = z.y = z.z = z.w = 0;
        *(ushort4*)dst = z;
      }
    }
  }
  __syncthreads();

  f32x4 outacc[4][4];
  #pragma unroll
  for (int m = 0; m < 4; m++)
    #pragma unroll
    for (int n = 0; n < 4; n++) outacc[m][n] = fzero;

  for (int h = 0; h < 8; ++h){
    // ---------------- Q projection pass (16 acc regs) ----------------
    {
      f32x4 aq[4];
      #pragma unroll
      for (int m = 0; m < 4; m++) aq[m] = fzero;
      const uint16_t* pq = WqkvT + (size_t)(h*64 + wave*16 + lo)*256;
      #pragma unroll
      for (int k0 = 0; k0 < 256; k0 += 32){
        const int kb = k0 + g*8;
        bf16x8 afr[4];
        #pragma unroll
        for (int m = 0; m < 4; m++){
          int row = m*16 + lo;
          if (m == 3) row = (row < 49) ? row : 49;   // xn row 49 = zeros
          afr[m] = LDS_LD8X(xn, row, kb);
        }
        bf16x8 fq = __builtin_bit_cast(bf16x8, *(const uint4*)(pq + kb));
        #pragma unroll
        for (int m = 0; m < 4; m++)
          aq[m] = __builtin_amdgcn_mfma_f32_16x16x32_bf16(afr[m], fq, aq[m], 0, 0, 0);
      }
      const int d = wave*16 + lo;
      #pragma unroll
      for (int m = 0; m < 4; m++){
        #pragma unroll
        for (int r = 0; r < 4; r++){
          const int token = m*16 + g*4 + r;
          const int tok   = (token < 49) ? token : 49;   // racers write identical values
          *(uint16_t*)((char*)qs + tok*128 + ((d*2) ^ ((tok&7)<<4))) = f2bf(aq[m][r]*0.125f);
        }
      }
    }
    // ---------------- K projection pass (16 acc regs) ----------------
    {
      f32x4 ak[4];
      #pragma unroll
      for (int m = 0; m < 4; m++) ak[m] = fzero;
      const uint16_t* pk = WqkvT + (size_t)(512 + h*64 + wave*16 + lo)*256;
      #pragma unroll
      for (int k0 = 0; k0 < 256; k0 += 32){
        const int kb = k0 + g*8;
        bf16x8 afr[4];
        #pragma unroll
        for (int m = 0; m < 4; m++){
          int row = m*16 + lo;
          if (m == 3) row = (row < 49) ? row : 49;
          afr[m] = LDS_LD8X(xn, row, kb);
        }
        bf16x8 fk = __builtin_bit_cast(bf16x8, *(const uint4*)(pk + kb));
        #pragma unroll
        for (int m = 0; m < 4; m++)
          ak[m] = __builtin_amdgcn_mfma_f32_16x16x32_bf16(afr[m], fk, ak[m], 0, 0, 0);
      }
      const int d = wave*16 + lo;
      #pragma unroll
      for (int m = 0; m < 4; m++){
        #pragma unroll
        for (int r = 0; r < 4; r++){
          const int token = m*16 + g*4 + r;
          const int tok   = (token < 49) ? token : 49;
          *(uint16_t*)((char*)ks + tok*128 + ((d*2) ^ ((tok&7)<<4))) = f2bf(ak[m][r]);
        }
      }
    }
    // ---------------- V projection pass (16 acc regs) ----------------
    {
      f32x4 av[4];
      #pragma unroll
      for (int m = 0; m < 4; m++) av[m] = fzero;
      const uint16_t* pv = WqkvT + (size_t)(1024 + h*64 + wave*16 + lo)*256;
      #pragma unroll
      for (int k0 = 0; k0 < 256; k0 += 32){
        const int kb = k0 + g*8;
        bf16x8 afr[4];
        #pragma unroll
        for (int m = 0; m < 4; m++){
          int row = m*16 + lo;
          if (m == 3) row = (row < 49) ? row : 49;
          afr[m] = LDS_LD8X(xn, row, kb);
        }
        bf16x8 fv = __builtin_bit_cast(bf16x8, *(const uint4*)(pv + kb));
        #pragma unroll
        for (int m = 0; m < 4; m++)
          av[m] = __builtin_amdgcn_mfma_f32_16x16x32_bf16(afr[m], fv, av[m], 0, 0, 0);
      }
      const int d = wave*16 + lo;
      #pragma unroll
      for (int m = 0; m < 4; m++){
        #pragma unroll
        for (int r = 0; r < 4; r++){
          const int token = m*16 + g*4 + r;
          *(uint16_t*)((char*)vt + d*128 + ((token*2) ^ ((d&7)<<4))) = f2bf(av[m][r]);
        }
      }
    }
    __syncthreads();   // (i) qs/ks/vt complete

    // ---------------- S = q k^T (+bias, mask) ----------------
    f32x4 s[4];
    #pragma unroll
    for (int n = 0; n < 4; n++) s[n] = fzero;
    {
      int qrow = wave*16 + lo; qrow = (qrow < 49) ? qrow : 49;
      bf16x8 a0 = LDS_LD8(qs, qrow, g*8);
      bf16x8 a1 = LDS_LD8(qs, qrow, 32 + g*8);
      #pragma unroll
      for (int n = 0; n < 4; n++){
        int krow = n*16 + lo;
        if (n == 3) krow = (krow < 49) ? krow : 49;
        bf16x8 b0 = LDS_LD8(ks, krow, g*8);
        bf16x8 b1 = LDS_LD8(ks, krow, 32 + g*8);
        s[n] = __builtin_amdgcn_mfma_f32_16x16x32_bf16(a0, b0, s[n], 0, 0, 0);
        s[n] = __builtin_amdgcn_mfma_f32_16x16x32_bf16(a1, b1, s[n], 0, 0, 0);
      }
    }
    {
      const float* bp = biasPre + h*2401;
      #pragma unroll
      for (int n = 0; n < 4; n++){
        const int j = n*16 + lo;
        #pragma unroll
        for (int r = 0; r < 4; r++){
          const int i = wave*16 + g*4 + r;
          float v = s[n][r];
          if (j < NTOK){ if (i < NTOK) v += bp[i*49 + j]; }
          else v = -1e30f;
          s[n][r] = v;
        }
      }
      // softmax over j: each score row lives in one 16-lane group
      float mx[4], sm[4];
      #pragma unroll
      for (int r = 0; r < 4; r++){
        float m0 = fmaxf(fmaxf(s[0][r], s[1][r]), fmaxf(s[2][r], s[3][r]));
        #pragma unroll
        for (int d = 1; d < 16; d <<= 1) m0 = fmaxf(m0, __shfl_xor(m0, d));
        mx[r] = m0;
        sm[r] = 0.f;
      }
      #pragma unroll
      for (int n = 0; n < 4; n++)
        #pragma unroll
        for (int r = 0; r < 4; r++){ float p = __expf(s[n][r] - mx[r]); s[n][r] = p; sm[r] += p; }
      #pragma unroll
      for (int r = 0; r < 4; r++){
        float t = sm[r];
        #pragma unroll
        for (int d = 1; d < 16; d <<= 1) t += __shfl_xor(t, d);
        sm[r] = 1.0f / t;
      }
      // write P (wave-private strip -> no barrier before PV)
      #pragma unroll
      for (int n = 0; n < 4; n++){
        const int j = n*16 + lo;
        #pragma unroll
        for (int r = 0; r < 4; r++){
          int i = wave*16 + g*4 + r; i = (i < 49) ? i : 49;  // racers identical
          *(uint16_t*)((char*)ps + i*128 + ((j*2) ^ ((i&7)<<4))) = f2bf(s[n][r]*sm[r]);
        }
      }
    }

    // ---------------- O = P V ----------------
    f32x4 o[4];
    #pragma unroll
    for (int n = 0; n < 4; n++) o[n] = fzero;
    {
      int prow = wave*16 + lo; prow = (prow < 49) ? prow : 49;
      bf16x8 a0 = LDS_LD8(ps, prow, g*8);
      bf16x8 a1 = LDS_LD8(ps, prow, 32 + g*8);
      #pragma unroll
      for (int n = 0; n < 4; n++){
        const int vrow = n*16 + lo;
        bf16x8 b0 = LDS_LD8(vt, vrow, g*8);
        bf16x8 b1 = LDS_LD8(vt, vrow, 32 + g*8);
        o[n] = __builtin_amdgcn_mfma_f32_16x16x32_bf16(a0, b0, o[n], 0, 0, 0);
        o[n] = __builtin_amdgcn_mfma_f32_16x16x32_bf16(a1, b1, o[n], 0, 0, 0);
      }
    }
    // write O_h into ps (own strip; own wave already consumed its P rows)
    #pragma unroll
    for (int n = 0; n < 4; n++){
      const int d = n*16 + lo;
      #pragma unroll
      for (int r = 0; r < 4; r++){
        int token = wave*16 + g*4 + r; token = (token < 49) ? token : 49;  // racers identical
        *(uint16_t*)((char*)ps + token*128 + ((d*2) ^ ((token&7)<<4))) = f2bf(o[n][r]);
      }
    }
    __syncthreads();   // (ii) O_h complete (read cross-wave next)

    // ---------------- out-projection accumulate ----------------
    #pragma unroll
    for (int kk = 0; kk < 2; ++kk){
      const int kb = kk*32 + g*8;
      bf16x8 afr[4];
      #pragma unroll
      for (int m = 0; m < 4; m++){
        int row = m*16 + lo;
        if (m == 3) row = (row < 49) ? row : 49;
        afr[m] = LDS_LD8(ps, row, kb);
      }
      #pragma unroll
      for (int n = 0; n < 4; n++){
        const int ncol = wave*64 + n*16 + lo;
        bf16x8 bb = __builtin_bit_cast(bf16x8,
          *(const uint4*)(WoutT + (size_t)ncol*512 + h*64 + kb));
        #pragma unroll
        for (int m = 0; m < 4; m++)
          outacc[m][n] = __builtin_amdgcn_mfma_f32_16x16x32_bf16(afr[m], bb, outacc[m][n], 0, 0, 0);
      }
    }
  }

  // ---------------- epilogue: +b_out, store fp32 ----------------
  #pragma unroll
  for (int n = 0; n < 4; n++){
    const int col = wave*64 + n*16 + lo;
    const float bo = bout[col];
    #pragma unroll
    for (int m = 0; m < 4; m++){
      #pragma unroll
      for (int r = 0; r < 4; r++){
        const int token = m*16 + g*4 + r;
        if (token < NTOK)
          out[((size_t)(b*NTOK + token))*256 + col] = outacc[m][n][r] + bo;
      }
    }
  }
}

extern "C" void kernel_launch(void* const* d_in, const int* in_sizes, int n_in,
                              void* d_out, int out_size, void* d_ws, size_t ws_size,
                              hipStream_t stream){
  const float* x     = (const float*)d_in[0];
  const float* gamma = (const float*)d_in[1];
  const float* beta  = (const float*)d_in[2];
  const float* Wqkv  = (const float*)d_in[3];
  const float* Wout  = (const float*)d_in[4];
  const float* bout  = (const float*)d_in[5];
  const float* btab  = (const float*)d_in[6];
  const int*   ridx  = (const int*)d_in[7];

  uint16_t* WqkvT   = (uint16_t*)d_ws;                          // 786432 B
  uint16_t* WoutT   = (uint16_t*)((char*)d_ws + 786432);        // 262144 B
  float*    biasPre = (float*)((char*)d_ws + 786432 + 262144);  // 76832 B

  prep_kernel<<<512, 256, 0, stream>>>(Wqkv, Wout, btab, ridx, WqkvT, WoutT, biasPre);
  maxvit_fused<<<4096, 256, 0, stream>>>(x, gamma, beta, WqkvT, WoutT, bout, biasPre,
                                         (float*)d_out);
}

// Round 13
// 1290.383 us; speedup vs baseline: 2.1564x; 1.2135x over previous
//
#include <hip/hip_runtime.h>
#include <hip/hip_bf16.h>
#include <stdint.h>

#define NTOK 49

typedef __bf16 bf16x8 __attribute__((ext_vector_type(8)));
typedef float f32x4 __attribute__((ext_vector_type(4)));

__device__ __forceinline__ uint16_t f2bf(float f){
  uint32_t x = __float_as_uint(f);
  uint32_t r = (x + 0x7fffu + ((x >> 16) & 1u)) >> 16;
  return (uint16_t)r;
}

// swizzled 16B read from a 64-wide (128B-stride) LDS tile
#define LDS_LD8(buf, row, kelem) \
  __builtin_bit_cast(bf16x8, *(const uint4*)((const char*)(buf) + (row)*128 + ((((kelem)*2)) ^ ((((row))&7)<<4))))
// swizzled 16B read from a 256-wide (512B-stride) LDS tile (xn)
#define LDS_LD8X(buf, row, kelem) \
  __builtin_bit_cast(bf16x8, *(const uint4*)((const char*)(buf) + (row)*512 + ((((kelem)*2)) ^ ((((row))&7)<<4))))
// swizzled 16B read from a 512-wide (1024B-stride) LDS tile (O in kernel B)
#define LDS_LD8O(buf, row, kelem) \
  __builtin_bit_cast(bf16x8, *(const uint4*)((const char*)(buf) + (row)*1024 + ((((kelem)*2)) ^ ((((row))&7)<<4))))

__global__ void prep_kernel(const float* __restrict__ Wqkv,
                            const float* __restrict__ Wout,
                            const float* __restrict__ btab,
                            const int* __restrict__ ridx,
                            uint16_t* __restrict__ WqkvT,
                            uint16_t* __restrict__ WoutT,
                            float* __restrict__ biasPre){
  const int T1 = 1536*256, T2 = 256*512, T3 = 8*2401;
  for (int i = blockIdx.x*blockDim.x + threadIdx.x; i < T1+T2+T3; i += gridDim.x*blockDim.x){
    if (i < T1){ int n = i/256, k = i%256; WqkvT[i] = f2bf(Wqkv[k*1536 + n]); }
    else if (i < T1+T2){ int j = i - T1; int n = j/512, k = j%512; WoutT[j] = f2bf(Wout[k*256 + n]); }
    else { int j = i - T1 - T2; int h = j/2401, ij = j%2401; biasPre[j] = btab[ridx[ij]*8 + h]; }
  }
}

// ============ Kernel A: LN + QKV proj + attention; O_h bf16 -> d_out staging ============
// LDS: xn 25600 + qs/ks/ps 6400*3 + vt 8192 = 52992 B -> 3 blocks/CU.
// No outacc (the 64-reg accumulator that blocked 3 waves/SIMD in R2..R12): peak acc = 48.
__global__ __launch_bounds__(256, 3)
void qkv_attn(const float* __restrict__ x,
              const float* __restrict__ gamma,
              const float* __restrict__ beta,
              const uint16_t* __restrict__ WqkvT,   // bf16 [1536][256]
              const float*    __restrict__ biasPre, // [8][49][49]
              uint16_t* __restrict__ Ostg)          // [B][49][512] bf16 (aliases d_out)
{
  __shared__ uint16_t xn[50*256];  // row 49 = zeros; reads of rows>49 clamp to 49
  __shared__ uint16_t qs[50*64];
  __shared__ uint16_t ks[50*64];
  __shared__ uint16_t ps[50*64];
  __shared__ uint16_t vt[64*64];   // V transposed: [d][token]

  const int b    = blockIdx.x;
  const int tid  = threadIdx.x;
  const int wave = tid >> 6;
  const int lane = tid & 63;
  const int lo   = lane & 15;
  const int g    = lane >> 4;
  const f32x4 fzero = {0.f, 0.f, 0.f, 0.f};

  // ---------------- LayerNorm (proven R2/R5 math) ----------------
  {
    const int c0 = lane * 4;
    float4 gm = *(const float4*)(gamma + c0);
    float4 bt = *(const float4*)(beta  + c0);
    for (int r = wave; r < 50; r += 4){
      char* dst = (char*)xn + r*512 + ((c0*2) ^ ((r&7)<<4));
      if (r < NTOK){
        float4 u = *(const float4*)(x + ((size_t)(b*NTOK + r))*256 + c0);
        float s  = u.x+u.y+u.z+u.w;
        float ss = u.x*u.x+u.y*u.y+u.z*u.z+u.w*u.w;
        #pragma unroll
        for (int d = 1; d < 64; d <<= 1){ s += __shfl_xor(s, d); ss += __shfl_xor(ss, d); }
        float mu  = s  * (1.0f/256.0f);
        float var = ss * (1.0f/256.0f) - mu*mu;
        float rs  = rsqrtf(var + 1e-5f);
        ushort4 o;
        o.x = f2bf((u.x-mu)*rs*gm.x+bt.x);
        o.y = f2bf((u.y-mu)*rs*gm.y+bt.y);
        o.z = f2bf((u.z-mu)*rs*gm.z+bt.z);
        o.w = f2bf((u.w-mu)*rs*gm.w+bt.w);
        *(ushort4*)dst = o;
      } else {
        ushort4 z; z.x = z.y = z.z = z.w = 0;
        *(ushort4*)dst = z;
      }
    }
  }
  __syncthreads();

  for (int h = 0; h < 8; ++h){
    // ---------------- QKV projection (combined, 48 acc; proven R5 code) ----------------
    {
      f32x4 aq[4], ak[4], av[4];
      #pragma unroll
      for (int m = 0; m < 4; m++){ aq[m] = fzero; ak[m] = fzero; av[m] = fzero; }
      const uint16_t* pq = WqkvT + (size_t)(       h*64 + wave*16 + lo)*256;
      const uint16_t* pk = WqkvT + (size_t)( 512 + h*64 + wave*16 + lo)*256;
      const uint16_t* pv = WqkvT + (size_t)(1024 + h*64 + wave*16 + lo)*256;
      #pragma unroll
      for (int k0 = 0; k0 < 256; k0 += 32){
        const int kb = k0 + g*8;
        bf16x8 afr[4];
        #pragma unroll
        for (int m = 0; m < 4; m++){
          int row = m*16 + lo;
          if (m == 3) row = (row < 49) ? row : 49;   // xn row 49 = zeros
          afr[m] = LDS_LD8X(xn, row, kb);
        }
        bf16x8 fq = __builtin_bit_cast(bf16x8, *(const uint4*)(pq + kb));
        bf16x8 fk = __builtin_bit_cast(bf16x8, *(const uint4*)(pk + kb));
        bf16x8 fv = __builtin_bit_cast(bf16x8, *(const uint4*)(pv + kb));
        #pragma unroll
        for (int m = 0; m < 4; m++){
          aq[m] = __builtin_amdgcn_mfma_f32_16x16x32_bf16(afr[m], fq, aq[m], 0, 0, 0);
          ak[m] = __builtin_amdgcn_mfma_f32_16x16x32_bf16(afr[m], fk, ak[m], 0, 0, 0);
          av[m] = __builtin_amdgcn_mfma_f32_16x16x32_bf16(afr[m], fv, av[m], 0, 0, 0);
        }
      }
      const int d = wave*16 + lo;
      #pragma unroll
      for (int m = 0; m < 4; m++){
        #pragma unroll
        for (int r = 0; r < 4; r++){
          const int token = m*16 + g*4 + r;
          const int tok   = (token < 49) ? token : 49;   // racers write identical values
          *(uint16_t*)((char*)qs + tok*128 + ((d*2) ^ ((tok&7)<<4))) = f2bf(aq[m][r]*0.125f);
          *(uint16_t*)((char*)ks + tok*128 + ((d*2) ^ ((tok&7)<<4))) = f2bf(ak[m][r]);
          *(uint16_t*)((char*)vt + d*128 + ((token*2) ^ ((d&7)<<4))) = f2bf(av[m][r]);
        }
      }
    }
    __syncthreads();   // (i) qs/ks/vt complete

    // ---------------- S = q k^T (+bias, mask) ----------------
    f32x4 s[4];
    #pragma unroll
    for (int n = 0; n < 4; n++) s[n] = fzero;
    {
      int qrow = wave*16 + lo; qrow = (qrow < 49) ? qrow : 49;
      bf16x8 a0 = LDS_LD8(qs, qrow, g*8);
      bf16x8 a1 = LDS_LD8(qs, qrow, 32 + g*8);
      #pragma unroll
      for (int n = 0; n < 4; n++){
        int krow = n*16 + lo;
        if (n == 3) krow = (krow < 49) ? krow : 49;
        bf16x8 b0 = LDS_LD8(ks, krow, g*8);
        bf16x8 b1 = LDS_LD8(ks, krow, 32 + g*8);
        s[n] = __builtin_amdgcn_mfma_f32_16x16x32_bf16(a0, b0, s[n], 0, 0, 0);
        s[n] = __builtin_amdgcn_mfma_f32_16x16x32_bf16(a1, b1, s[n], 0, 0, 0);
      }
    }
    {
      const float* bp = biasPre + h*2401;
      #pragma unroll
      for (int n = 0; n < 4; n++){
        const int j = n*16 + lo;
        #pragma unroll
        for (int r = 0; r < 4; r++){
          const int i = wave*16 + g*4 + r;
          float v = s[n][r];
          if (j < NTOK){ if (i < NTOK) v += bp[i*49 + j]; }
          else v = -1e30f;
          s[n][r] = v;
        }
      }
      // softmax over j: each score row lives in one 16-lane group
      float mx[4], sm[4];
      #pragma unroll
      for (int r = 0; r < 4; r++){
        float m0 = fmaxf(fmaxf(s[0][r], s[1][r]), fmaxf(s[2][r], s[3][r]));
        #pragma unroll
        for (int d = 1; d < 16; d <<= 1) m0 = fmaxf(m0, __shfl_xor(m0, d));
        mx[r] = m0;
        sm[r] = 0.f;
      }
      #pragma unroll
      for (int n = 0; n < 4; n++)
        #pragma unroll
        for (int r = 0; r < 4; r++){ float p = __expf(s[n][r] - mx[r]); s[n][r] = p; sm[r] += p; }
      #pragma unroll
      for (int r = 0; r < 4; r++){
        float t = sm[r];
        #pragma unroll
        for (int d = 1; d < 16; d <<= 1) t += __shfl_xor(t, d);
        sm[r] = 1.0f / t;
      }
      // write P (wave-private strip -> no barrier before PV)
      #pragma unroll
      for (int n = 0; n < 4; n++){
        const int j = n*16 + lo;
        #pragma unroll
        for (int r = 0; r < 4; r++){
          int i = wave*16 + g*4 + r; i = (i < 49) ? i : 49;  // racers identical
          *(uint16_t*)((char*)ps + i*128 + ((j*2) ^ ((i&7)<<4))) = f2bf(s[n][r]*sm[r]);
        }
      }
    }

    // ---------------- O = P V -> global staging (bf16) ----------------
    f32x4 o[4];
    #pragma unroll
    for (int n = 0; n < 4; n++) o[n] = fzero;
    {
      int prow = wave*16 + lo; prow = (prow < 49) ? prow : 49;
      bf16x8 a0 = LDS_LD8(ps, prow, g*8);
      bf16x8 a1 = LDS_LD8(ps, prow, 32 + g*8);
      #pragma unroll
      for (int n = 0; n < 4; n++){
        const int vrow = n*16 + lo;
        bf16x8 b0 = LDS_LD8(vt, vrow, g*8);
        bf16x8 b1 = LDS_LD8(vt, vrow, 32 + g*8);
        o[n] = __builtin_amdgcn_mfma_f32_16x16x32_bf16(a0, b0, o[n], 0, 0, 0);
        o[n] = __builtin_amdgcn_mfma_f32_16x16x32_bf16(a1, b1, o[n], 0, 0, 0);
      }
    }
    {
      uint16_t* owin = Ostg + (size_t)b*(NTOK*512);
      #pragma unroll
      for (int n = 0; n < 4; n++){
        const int d = n*16 + lo;
        #pragma unroll
        for (int r = 0; r < 4; r++){
          const int token = wave*16 + g*4 + r;
          if (token < NTOK)
            owin[token*512 + h*64 + d] = f2bf(o[n][r]);
        }
      }
    }
    __syncthreads();   // (ii) all waves done reading qs/ks/vt before next head's proj
  }
}

// ============ Kernel B: out-projection, in-place over d_out ============
// Stages own O window (bf16) into swizzled LDS, then 49x512x256 GEMM, writes fp32 in place.
__global__ __launch_bounds__(256, 2)
void outproj(const uint16_t* __restrict__ Ostg,    // [B][49][512] bf16 (aliases d_out)
             const uint16_t* __restrict__ WoutT,   // [256][512] bf16
             const float*    __restrict__ bout,
             float* __restrict__ out)               // [B][49][256] fp32 (same bytes)
{
  __shared__ uint16_t os[50*512];   // 51200 B; row 49 = zeros; 1024B-stride rows, swizzled

  const int b    = blockIdx.x;
  const int tid  = threadIdx.x;
  const int wave = tid >> 6;
  const int lane = tid & 63;
  const int lo   = lane & 15;
  const int g    = lane >> 4;
  const f32x4 fzero = {0.f, 0.f, 0.f, 0.f};

  // stage O window: 50 rows x 64 chunks of 16B
  {
    const uint16_t* src = Ostg + (size_t)b*(NTOK*512);
    for (int idx = tid; idx < 50*64; idx += 256){
      const int row = idx >> 6;
      const int c   = idx & 63;
      uint4 v;
      if (row < NTOK) v = *(const uint4*)(src + (size_t)row*512 + c*8);
      else { v.x = v.y = v.z = v.w = 0u; }
      *(uint4*)((char*)os + row*1024 + ((c*16) ^ ((row&7)<<4))) = v;
    }
  }
  __syncthreads();   // full window read into LDS before any in-place write

  f32x4 outacc[4][4];
  #pragma unroll
  for (int m = 0; m < 4; m++)
    #pragma unroll
    for (int n = 0; n < 4; n++) outacc[m][n] = fzero;

  #pragma unroll
  for (int k0 = 0; k0 < 512; k0 += 32){
    const int kb = k0 + g*8;
    bf16x8 afr[4];
    #pragma unroll
    for (int m = 0; m < 4; m++){
      int row = m*16 + lo;
      if (m == 3) row = (row < 49) ? row : 49;   // row 49 zeros
      afr[m] = LDS_LD8O(os, row, kb);
    }
    #pragma unroll
    for (int n = 0; n < 4; n++){
      const int ncol = wave*64 + n*16 + lo;
      bf16x8 bb = __builtin_bit_cast(bf16x8,
        *(const uint4*)(WoutT + (size_t)ncol*512 + kb));
      #pragma unroll
      for (int m = 0; m < 4; m++)
        outacc[m][n] = __builtin_amdgcn_mfma_f32_16x16x32_bf16(afr[m], bb, outacc[m][n], 0, 0, 0);
    }
  }

  // epilogue: +b_out, fp32 in place
  #pragma unroll
  for (int n = 0; n < 4; n++){
    const int col = wave*64 + n*16 + lo;
    const float bo = bout[col];
    #pragma unroll
    for (int m = 0; m < 4; m++){
      #pragma unroll
      for (int r = 0; r < 4; r++){
        const int token = m*16 + g*4 + r;
        if (token < NTOK)
          out[((size_t)b*NTOK + token)*256 + col] = outacc[m][n][r] + bo;
      }
    }
  }
}

extern "C" void kernel_launch(void* const* d_in, const int* in_sizes, int n_in,
                              void* d_out, int out_size, void* d_ws, size_t ws_size,
                              hipStream_t stream){
  const float* x     = (const float*)d_in[0];
  const float* gamma = (const float*)d_in[1];
  const float* beta  = (const float*)d_in[2];
  const float* Wqkv  = (const float*)d_in[3];
  const float* Wout  = (const float*)d_in[4];
  const float* bout  = (const float*)d_in[5];
  const float* btab  = (const float*)d_in[6];
  const int*   ridx  = (const int*)d_in[7];

  uint16_t* WqkvT   = (uint16_t*)d_ws;                          // 786432 B
  uint16_t* WoutT   = (uint16_t*)((char*)d_ws + 786432);        // 262144 B
  float*    biasPre = (float*)((char*)d_ws + 786432 + 262144);  // 76832 B

  // d_out doubles as bf16 O staging: 4096 windows * 49*512*2B = exactly out_size*4 bytes.
  uint16_t* Ostg = (uint16_t*)d_out;

  prep_kernel<<<512, 256, 0, stream>>>(Wqkv, Wout, btab, ridx, WqkvT, WoutT, biasPre);
  qkv_attn<<<4096, 256, 0, stream>>>(x, gamma, beta, WqkvT, biasPre, Ostg);
  outproj<<<4096, 256, 0, stream>>>(Ostg, WoutT, bout, (float*)d_out);
}

// Round 14
// 879.066 us; speedup vs baseline: 3.1654x; 1.4679x over previous
//
#include <hip/hip_runtime.h>
#include <hip/hip_bf16.h>
#include <stdint.h>

#define NTOK 49

typedef __bf16 bf16x8 __attribute__((ext_vector_type(8)));
typedef float f32x4 __attribute__((ext_vector_type(4)));

__device__ __forceinline__ uint16_t f2bf(float f){
  uint32_t x = __float_as_uint(f);
  uint32_t r = (x + 0x7fffu + ((x >> 16) & 1u)) >> 16;
  return (uint16_t)r;
}

// swizzled 16B read from a 64-wide (128B-stride) LDS tile
#define LDS_LD8(buf, row, kelem) \
  __builtin_bit_cast(bf16x8, *(const uint4*)((const char*)(buf) + (row)*128 + ((((kelem)*2)) ^ ((((row))&7)<<4))))
// swizzled 16B read from a 256-wide (512B-stride) LDS tile (xn)
#define LDS_LD8X(buf, row, kelem) \
  __builtin_bit_cast(bf16x8, *(const uint4*)((const char*)(buf) + (row)*512 + ((((kelem)*2)) ^ ((((row))&7)<<4))))
// swizzled 16B read from a 512-wide (1024B-stride) LDS tile (O in kernel B)
#define LDS_LD8O(buf, row, kelem) \
  __builtin_bit_cast(bf16x8, *(const uint4*)((const char*)(buf) + (row)*1024 + ((((kelem)*2)) ^ ((((row))&7)<<4))))

__global__ void prep_kernel(const float* __restrict__ Wqkv,
                            const float* __restrict__ Wout,
                            const float* __restrict__ btab,
                            const int* __restrict__ ridx,
                            uint16_t* __restrict__ WqkvT,
                            uint16_t* __restrict__ WoutT,
                            float* __restrict__ biasPre){
  const int T1 = 1536*256, T2 = 256*512, T3 = 8*2401;
  for (int i = blockIdx.x*blockDim.x + threadIdx.x; i < T1+T2+T3; i += gridDim.x*blockDim.x){
    if (i < T1){ int n = i/256, k = i%256; WqkvT[i] = f2bf(Wqkv[k*1536 + n]); }
    else if (i < T1+T2){ int j = i - T1; int n = j/512, k = j%512; WoutT[j] = f2bf(Wout[k*256 + n]); }
    else { int j = i - T1 - T2; int h = j/2401, ij = j%2401; biasPre[j] = btab[ridx[ij]*8 + h]; }
  }
}

// ============ Kernel A: LN + 3-pass QKV proj + attention; O_h bf16 -> d_out staging ============
// LDS 52992 B -> 3 blocks/CU. Acc concurrency <= 16 at all times (3-pass proj, R11-proven;
// no outacc, R13-proven) so the (256,3) split leaves ~150 arch regs -- enough for the
// ~110-130 demand. R11 (acc 80) and R13-A (acc 48) both got arch capped at 84 -> spill.
__global__ __launch_bounds__(256, 3)
void qkv_attn(const float* __restrict__ x,
              const float* __restrict__ gamma,
              const float* __restrict__ beta,
              const uint16_t* __restrict__ WqkvT,   // bf16 [1536][256]
              const float*    __restrict__ biasPre, // [8][49][49]
              uint16_t* __restrict__ Ostg)          // [B][49][512] bf16 (aliases d_out)
{
  __shared__ uint16_t xn[50*256];  // row 49 = zeros; reads of rows>49 clamp to 49
  __shared__ uint16_t qs[50*64];
  __shared__ uint16_t ks[50*64];
  __shared__ uint16_t ps[50*64];
  __shared__ uint16_t vt[64*64];   // V transposed: [d][token]

  const int b    = blockIdx.x;
  const int tid  = threadIdx.x;
  const int wave = tid >> 6;
  const int lane = tid & 63;
  const int lo   = lane & 15;
  const int g    = lane >> 4;
  const f32x4 fzero = {0.f, 0.f, 0.f, 0.f};

  // ---------------- LayerNorm (proven R2/R5 math) ----------------
  {
    const int c0 = lane * 4;
    float4 gm = *(const float4*)(gamma + c0);
    float4 bt = *(const float4*)(beta  + c0);
    for (int r = wave; r < 50; r += 4){
      char* dst = (char*)xn + r*512 + ((c0*2) ^ ((r&7)<<4));
      if (r < NTOK){
        float4 u = *(const float4*)(x + ((size_t)(b*NTOK + r))*256 + c0);
        float s  = u.x+u.y+u.z+u.w;
        float ss = u.x*u.x+u.y*u.y+u.z*u.z+u.w*u.w;
        #pragma unroll
        for (int d = 1; d < 64; d <<= 1){ s += __shfl_xor(s, d); ss += __shfl_xor(ss, d); }
        float mu  = s  * (1.0f/256.0f);
        float var = ss * (1.0f/256.0f) - mu*mu;
        float rs  = rsqrtf(var + 1e-5f);
        ushort4 o;
        o.x = f2bf((u.x-mu)*rs*gm.x+bt.x);
        o.y = f2bf((u.y-mu)*rs*gm.y+bt.y);
        o.z = f2bf((u.z-mu)*rs*gm.z+bt.z);
        o.w = f2bf((u.w-mu)*rs*gm.w+bt.w);
        *(ushort4*)dst = o;
      } else {
        ushort4 z; z.x = z.y = z.z = z.w = 0;
        *(ushort4*)dst = z;
      }
    }
  }
  __syncthreads();

  for (int h = 0; h < 8; ++h){
    // ---------------- Q projection pass (16 acc) ----------------
    {
      f32x4 aq[4];
      #pragma unroll
      for (int m = 0; m < 4; m++) aq[m] = fzero;
      const uint16_t* pq = WqkvT + (size_t)(h*64 + wave*16 + lo)*256;
      #pragma unroll
      for (int k0 = 0; k0 < 256; k0 += 32){
        const int kb = k0 + g*8;
        bf16x8 afr[4];
        #pragma unroll
        for (int m = 0; m < 4; m++){
          int row = m*16 + lo;
          if (m == 3) row = (row < 49) ? row : 49;   // xn row 49 = zeros
          afr[m] = LDS_LD8X(xn, row, kb);
        }
        bf16x8 fq = __builtin_bit_cast(bf16x8, *(const uint4*)(pq + kb));
        #pragma unroll
        for (int m = 0; m < 4; m++)
          aq[m] = __builtin_amdgcn_mfma_f32_16x16x32_bf16(afr[m], fq, aq[m], 0, 0, 0);
      }
      const int d = wave*16 + lo;
      #pragma unroll
      for (int m = 0; m < 4; m++){
        #pragma unroll
        for (int r = 0; r < 4; r++){
          const int token = m*16 + g*4 + r;
          const int tok   = (token < 49) ? token : 49;   // racers write identical values
          *(uint16_t*)((char*)qs + tok*128 + ((d*2) ^ ((tok&7)<<4))) = f2bf(aq[m][r]*0.125f);
        }
      }
    }
    // ---------------- K projection pass (16 acc) ----------------
    {
      f32x4 ak[4];
      #pragma unroll
      for (int m = 0; m < 4; m++) ak[m] = fzero;
      const uint16_t* pk = WqkvT + (size_t)(512 + h*64 + wave*16 + lo)*256;
      #pragma unroll
      for (int k0 = 0; k0 < 256; k0 += 32){
        const int kb = k0 + g*8;
        bf16x8 afr[4];
        #pragma unroll
        for (int m = 0; m < 4; m++){
          int row = m*16 + lo;
          if (m == 3) row = (row < 49) ? row : 49;
          afr[m] = LDS_LD8X(xn, row, kb);
        }
        bf16x8 fk = __builtin_bit_cast(bf16x8, *(const uint4*)(pk + kb));
        #pragma unroll
        for (int m = 0; m < 4; m++)
          ak[m] = __builtin_amdgcn_mfma_f32_16x16x32_bf16(afr[m], fk, ak[m], 0, 0, 0);
      }
      const int d = wave*16 + lo;
      #pragma unroll
      for (int m = 0; m < 4; m++){
        #pragma unroll
        for (int r = 0; r < 4; r++){
          const int token = m*16 + g*4 + r;
          const int tok   = (token < 49) ? token : 49;
          *(uint16_t*)((char*)ks + tok*128 + ((d*2) ^ ((tok&7)<<4))) = f2bf(ak[m][r]);
        }
      }
    }
    // ---------------- V projection pass (16 acc) ----------------
    {
      f32x4 av[4];
      #pragma unroll
      for (int m = 0; m < 4; m++) av[m] = fzero;
      const uint16_t* pv = WqkvT + (size_t)(1024 + h*64 + wave*16 + lo)*256;
      #pragma unroll
      for (int k0 = 0; k0 < 256; k0 += 32){
        const int kb = k0 + g*8;
        bf16x8 afr[4];
        #pragma unroll
        for (int m = 0; m < 4; m++){
          int row = m*16 + lo;
          if (m == 3) row = (row < 49) ? row : 49;
          afr[m] = LDS_LD8X(xn, row, kb);
        }
        bf16x8 fv = __builtin_bit_cast(bf16x8, *(const uint4*)(pv + kb));
        #pragma unroll
        for (int m = 0; m < 4; m++)
          av[m] = __builtin_amdgcn_mfma_f32_16x16x32_bf16(afr[m], fv, av[m], 0, 0, 0);
      }
      const int d = wave*16 + lo;
      #pragma unroll
      for (int m = 0; m < 4; m++){
        #pragma unroll
        for (int r = 0; r < 4; r++){
          const int token = m*16 + g*4 + r;
          *(uint16_t*)((char*)vt + d*128 + ((token*2) ^ ((d&7)<<4))) = f2bf(av[m][r]);
        }
      }
    }
    __syncthreads();   // (i) qs/ks/vt complete

    // ---------------- S = q k^T (+bias, mask) ----------------
    f32x4 s[4];
    #pragma unroll
    for (int n = 0; n < 4; n++) s[n] = fzero;
    {
      int qrow = wave*16 + lo; qrow = (qrow < 49) ? qrow : 49;
      bf16x8 a0 = LDS_LD8(qs, qrow, g*8);
      bf16x8 a1 = LDS_LD8(qs, qrow, 32 + g*8);
      #pragma unroll
      for (int n = 0; n < 4; n++){
        int krow = n*16 + lo;
        if (n == 3) krow = (krow < 49) ? krow : 49;
        bf16x8 b0 = LDS_LD8(ks, krow, g*8);
        bf16x8 b1 = LDS_LD8(ks, krow, 32 + g*8);
        s[n] = __builtin_amdgcn_mfma_f32_16x16x32_bf16(a0, b0, s[n], 0, 0, 0);
        s[n] = __builtin_amdgcn_mfma_f32_16x16x32_bf16(a1, b1, s[n], 0, 0, 0);
      }
    }
    {
      const float* bp = biasPre + h*2401;
      #pragma unroll
      for (int n = 0; n < 4; n++){
        const int j = n*16 + lo;
        #pragma unroll
        for (int r = 0; r < 4; r++){
          const int i = wave*16 + g*4 + r;
          float v = s[n][r];
          if (j < NTOK){ if (i < NTOK) v += bp[i*49 + j]; }
          else v = -1e30f;
          s[n][r] = v;
        }
      }
      // softmax over j: each score row lives in one 16-lane group
      float mx[4], sm[4];
      #pragma unroll
      for (int r = 0; r < 4; r++){
        float m0 = fmaxf(fmaxf(s[0][r], s[1][r]), fmaxf(s[2][r], s[3][r]));
        #pragma unroll
        for (int d = 1; d < 16; d <<= 1) m0 = fmaxf(m0, __shfl_xor(m0, d));
        mx[r] = m0;
        sm[r] = 0.f;
      }
      #pragma unroll
      for (int n = 0; n < 4; n++)
        #pragma unroll
        for (int r = 0; r < 4; r++){ float p = __expf(s[n][r] - mx[r]); s[n][r] = p; sm[r] += p; }
      #pragma unroll
      for (int r = 0; r < 4; r++){
        float t = sm[r];
        #pragma unroll
        for (int d = 1; d < 16; d <<= 1) t += __shfl_xor(t, d);
        sm[r] = 1.0f / t;
      }
      // write P (wave-private strip -> no barrier before PV)
      #pragma unroll
      for (int n = 0; n < 4; n++){
        const int j = n*16 + lo;
        #pragma unroll
        for (int r = 0; r < 4; r++){
          int i = wave*16 + g*4 + r; i = (i < 49) ? i : 49;  // racers identical
          *(uint16_t*)((char*)ps + i*128 + ((j*2) ^ ((i&7)<<4))) = f2bf(s[n][r]*sm[r]);
        }
      }
    }

    // ---------------- O = P V -> global staging (bf16) ----------------
    f32x4 o[4];
    #pragma unroll
    for (int n = 0; n < 4; n++) o[n] = fzero;
    {
      int prow = wave*16 + lo; prow = (prow < 49) ? prow : 49;
      bf16x8 a0 = LDS_LD8(ps, prow, g*8);
      bf16x8 a1 = LDS_LD8(ps, prow, 32 + g*8);
      #pragma unroll
      for (int n = 0; n < 4; n++){
        const int vrow = n*16 + lo;
        bf16x8 b0 = LDS_LD8(vt, vrow, g*8);
        bf16x8 b1 = LDS_LD8(vt, vrow, 32 + g*8);
        o[n] = __builtin_amdgcn_mfma_f32_16x16x32_bf16(a0, b0, o[n], 0, 0, 0);
        o[n] = __builtin_amdgcn_mfma_f32_16x16x32_bf16(a1, b1, o[n], 0, 0, 0);
      }
    }
    {
      uint16_t* owin = Ostg + (size_t)b*(NTOK*512);
      #pragma unroll
      for (int n = 0; n < 4; n++){
        const int d = n*16 + lo;
        #pragma unroll
        for (int r = 0; r < 4; r++){
          const int token = wave*16 + g*4 + r;
          if (token < NTOK)
            owin[token*512 + h*64 + d] = f2bf(o[n][r]);
        }
      }
    }
    __syncthreads();   // (ii) all waves done reading qs/ks/vt before next head's proj
  }
}

// ============ Kernel B: out-projection, in-place over d_out (R13-proven) ============
__global__ __launch_bounds__(256, 2)
void outproj(const uint16_t* __restrict__ Ostg,    // [B][49][512] bf16 (aliases d_out)
             const uint16_t* __restrict__ WoutT,   // [256][512] bf16
             const float*    __restrict__ bout,
             float* __restrict__ out)               // [B][49][256] fp32 (same bytes)
{
  __shared__ uint16_t os[50*512];   // 51200 B; row 49 = zeros

  const int b    = blockIdx.x;
  const int tid  = threadIdx.x;
  const int wave = tid >> 6;
  const int lane = tid & 63;
  const int lo   = lane & 15;
  const int g    = lane >> 4;
  const f32x4 fzero = {0.f, 0.f, 0.f, 0.f};

  // stage O window: 50 rows x 64 chunks of 16B
  {
    const uint16_t* src = Ostg + (size_t)b*(NTOK*512);
    for (int idx = tid; idx < 50*64; idx += 256){
      const int row = idx >> 6;
      const int c   = idx & 63;
      uint4 v;
      if (row < NTOK) v = *(const uint4*)(src + (size_t)row*512 + c*8);
      else { v.x = v.y = v.z = v.w = 0u; }
      *(uint4*)((char*)os + row*1024 + ((c*16) ^ ((row&7)<<4))) = v;
    }
  }
  __syncthreads();   // full window read into LDS before any in-place write

  f32x4 outacc[4][4];
  #pragma unroll
  for (int m = 0; m < 4; m++)
    #pragma unroll
    for (int n = 0; n < 4; n++) outacc[m][n] = fzero;

  #pragma unroll
  for (int k0 = 0; k0 < 512; k0 += 32){
    const int kb = k0 + g*8;
    bf16x8 afr[4];
    #pragma unroll
    for (int m = 0; m < 4; m++){
      int row = m*16 + lo;
      if (m == 3) row = (row < 49) ? row : 49;   // row 49 zeros
      afr[m] = LDS_LD8O(os, row, kb);
    }
    #pragma unroll
    for (int n = 0; n < 4; n++){
      const int ncol = wave*64 + n*16 + lo;
      bf16x8 bb = __builtin_bit_cast(bf16x8,
        *(const uint4*)(WoutT + (size_t)ncol*512 + kb));
      #pragma unroll
      for (int m = 0; m < 4; m++)
        outacc[m][n] = __builtin_amdgcn_mfma_f32_16x16x32_bf16(afr[m], bb, outacc[m][n], 0, 0, 0);
    }
  }

  // epilogue: +b_out, fp32 in place
  #pragma unroll
  for (int n = 0; n < 4; n++){
    const int col = wave*64 + n*16 + lo;
    const float bo = bout[col];
    #pragma unroll
    for (int m = 0; m < 4; m++){
      #pragma unroll
      for (int r = 0; r < 4; r++){
        const int token = m*16 + g*4 + r;
        if (token < NTOK)
          out[((size_t)b*NTOK + token)*256 + col] = outacc[m][n][r] + bo;
      }
    }
  }
}

extern "C" void kernel_launch(void* const* d_in, const int* in_sizes, int n_in,
                              void* d_out, int out_size, void* d_ws, size_t ws_size,
                              hipStream_t stream){
  const float* x     = (const float*)d_in[0];
  const float* gamma = (const float*)d_in[1];
  const float* beta  = (const float*)d_in[2];
  const float* Wqkv  = (const float*)d_in[3];
  const float* Wout  = (const float*)d_in[4];
  const float* bout  = (const float*)d_in[5];
  const float* btab  = (const float*)d_in[6];
  const int*   ridx  = (const int*)d_in[7];

  uint16_t* WqkvT   = (uint16_t*)d_ws;                          // 786432 B
  uint16_t* WoutT   = (uint16_t*)((char*)d_ws + 786432);        // 262144 B
  float*    biasPre = (float*)((char*)d_ws + 786432 + 262144);  // 76832 B

  // d_out doubles as bf16 O staging: 4096 windows * 49*512*2B = exactly out_size*4 bytes.
  uint16_t* Ostg = (uint16_t*)d_out;

  prep_kernel<<<512, 256, 0, stream>>>(Wqkv, Wout, btab, ridx, WqkvT, WoutT, biasPre);
  qkv_attn<<<4096, 256, 0, stream>>>(x, gamma, beta, WqkvT, biasPre, Ostg);
  outproj<<<4096, 256, 0, stream>>>(Ostg, WoutT, bout, (float*)d_out);
}